// Round 6
// baseline (69.472 us; speedup 1.0000x reference)
//
#include <hip/hip_runtime.h>

#define WIN_SIZE   400
#define WIN_SHIFT  160
#define BATCH      32
#define T_LEN      480000
#define NFRAMES    2998                  // (480000-400)/160 + 1
#define FTILE      64
#define NTILES     47                    // ceil(2998/64)
#define NBLOCKS    (NTILES * BATCH)      // 1504 = 8 * 188
#define PER_XCD    (NBLOCKS / 8)         // 188 = 4 whole batches of 47 tiles
#define SAMPLES    ((FTILE-1)*WIN_SHIFT + WIN_SIZE)   // 10480
#define SAMPLES_PAD 10496

typedef float f32x2 __attribute__((ext_vector_type(2)));

// XOR-swizzle: stride-160 (== 5*32 banks) reads would be 32-way conflicted.
// Compute reads a = 320*k2 + 160*j + w + r:
//   bank = ((160j+w+r)&31) ^ ((10*k2 + c)&31); gcd(10,32)=2 -> 16 banks x2
//   per row-half; r=0/1 separate via bit0 -> 2 lanes/bank = free (m136).
__device__ __forceinline__ int swz(int a) { return a ^ ((a >> 5) & 31); }

__global__ __launch_bounds__(256) void window_frame_kernel(
    const float* __restrict__ x, const float* __restrict__ window,
    float* __restrict__ out)
{
    __shared__ float lx[SAMPLES_PAD];
    __shared__ float lw[WIN_SIZE];

    // XCD-aware bijective swizzle: each XCD owns 188 consecutive (b,tile) ids
    // = 4 whole batches -> neighbor tiles share an L2.
    const int flat = blockIdx.x;
    const int lin  = (flat & 7) * PER_XCD + (flat >> 3);
    const int b    = lin / NTILES;
    const int k    = lin % NTILES;

    const long base  = (long)b * T_LEN + (long)k * FTILE * WIN_SHIFT;
    const int  avail = T_LEN - k * FTILE * WIN_SHIFT;    // multiple of 16
    const int  need  = min(SAMPLES, avail);
    const int  need4 = need >> 2;

    const int tid = threadIdx.x;

    for (int i = tid; i < WIN_SIZE; i += 256) lw[i] = window[i];

    // stage x: coalesced float4 loads -> swizzled scalar LDS writes
    const float4* __restrict__ xg = (const float4*)(x + base);
    for (int i4 = tid; i4 < need4; i4 += 256) {
        float4 v = xg[i4];
        int a = i4 << 2;
        lx[swz(a + 0)] = v.x;
        lx[swz(a + 1)] = v.y;
        lx[swz(a + 2)] = v.z;
        lx[swz(a + 3)] = v.w;
    }
    __syncthreads();

    const int lane = tid & 63;
    const int wid  = tid >> 6;
    const int k2   = lane & 31;          // frame-pair index: frames 2k2, 2k2+1
    const int r    = lane >> 5;          // row offset within wave's row-pair
    const int fr   = FTILE * k + 2 * k2;
    const bool ok  = fr < NFRAMES;       // tail tile: 54 frames = 27 whole pairs
    const int w0   = wid * 2 + r;
    const int a0   = 320 * k2;           // LDS offset of frame 2k2, col 0

    // row start (b*400+w)*2998 + 64k + 2k2 is always EVEN -> 8B-aligned
    // float2 stores everywhere. NONTEMPORAL: nt flag streams the write
    // (no L2 allocate / no fetch-on-write partial-line merge from HBM).
    float* op = out + ((long)b * WIN_SIZE + w0) * NFRAMES + fr;

    // wave covers rows {w0, w0+1} x 64 frames per pass; 50 passes.
    #pragma unroll 5
    for (int w = w0; w < WIN_SIZE; w += 8) {
        float lwv = lw[w];
        f32x2 v;
        v.x = lx[swz(a0 + w)]       * lwv;   // frame 2k2
        v.y = lx[swz(a0 + 160 + w)] * lwv;   // frame 2k2+1
        if (ok) __builtin_nontemporal_store(v, (f32x2*)op);
        op += 8L * NFRAMES;
    }
}

extern "C" void kernel_launch(void* const* d_in, const int* in_sizes, int n_in,
                              void* d_out, int out_size, void* d_ws, size_t ws_size,
                              hipStream_t stream) {
    const float* x      = (const float*)d_in[0];
    const float* window = (const float*)d_in[1];
    // d_in[2] = win_shift scalar (160) — compile-time constant here
    float* out = (float*)d_out;

    window_frame_kernel<<<NBLOCKS, 256, 0, stream>>>(x, window, out);
}

// Round 7
// 42.434 us; speedup vs baseline: 1.6372x; 1.6372x over previous
//
#include <hip/hip_runtime.h>

#define WIN_SIZE   400
#define WIN_SHIFT  160
#define BATCH      32
#define T_LEN      480000
#define NFRAMES    2998                  // (480000-400)/160 + 1
#define FTILE      64
#define NTILES     47
#define TILE_SAMP  (FTILE * WIN_SHIFT)   // 10240
#define SAMPLES    ((FTILE-1)*WIN_SHIFT + WIN_SIZE)   // 10480
#define SAMPLES4   (SAMPLES >> 2)        // 2620
#define SAMPLES_PAD 10496
#define NPAIRS     24                    // block j: tiles {2j, 2j+1}; j=23: tile 46 only
#define NBLOCKS    (NPAIRS * BATCH)      // 768 = 256 CUs * 3 = 8 XCD * 96
#define PER_XCD    (NBLOCKS / 8)         // 96 = 4 whole batches of 24

typedef float f32x2 __attribute__((ext_vector_type(2)));

// XOR-swizzle: stride-320-float reads (320 = 10*32 banks) would all hit one
// bank. bank(swz(320k2+w)) = (w&31) ^ ((10k2 + w>>5)&31); 10k2 mod 32 spans
// the 16 even residues x2 -> row-halves land even/odd banks -> 2 lanes/bank
// = free (m136). Staging writes a=4t+j: also 2 lanes/bank.
__device__ __forceinline__ int swz(int a) { return a ^ ((a >> 5) & 31); }

__device__ __forceinline__ void store_tile(
    const float* __restrict__ lx, const float* __restrict__ lw,
    float* __restrict__ out, int b, int k, int tid)
{
    const int lane = tid & 63;
    const int wid  = tid >> 6;
    const int k2   = lane & 31;          // frame-pair: frames 2k2, 2k2+1
    const int r    = lane >> 5;
    const int fr   = FTILE * k + 2 * k2;
    const bool ok  = fr < NFRAMES;       // tail tile: 54 frames = 27 pairs
    const int w0   = wid * 2 + r;
    const int a0   = 320 * k2;
    // row start (b*400+w)*2998 + 64k + 2k2 always even -> 8B-aligned float2
    float* op = out + ((long)b * WIN_SIZE + w0) * NFRAMES + fr;
    #pragma unroll 5
    for (int w = w0; w < WIN_SIZE; w += 8) {
        float lwv = lw[w];
        f32x2 v;
        v.x = lx[swz(a0 + w)]       * lwv;
        v.y = lx[swz(a0 + 160 + w)] * lwv;
        if (ok) *(f32x2*)op = v;
        op += 8L * NFRAMES;
    }
}

// 768 blocks = exactly 3 resident/CU for the whole kernel (no ramp rounds).
// Each block: stage A -> issue B's global loads to regs -> store A (B-load
// latency hides under it) -> LDS-write B -> store B.
__global__ __launch_bounds__(256) void window_frame_kernel(
    const float* __restrict__ x, const float* __restrict__ window,
    float* __restrict__ out)
{
    __shared__ float lx[SAMPLES_PAD];
    __shared__ float lw[WIN_SIZE];

    // XCD-aware bijective swizzle: each XCD owns 96 consecutive (b,pair) ids
    // = 4 whole batches -> neighbor tiles share an L2.
    const int flat = blockIdx.x;
    const int lin  = (flat & 7) * PER_XCD + (flat >> 3);
    const int b    = lin / NPAIRS;
    const int j    = lin % NPAIRS;
    const int kA   = 2 * j;
    const bool hasB = (j < NPAIRS - 1);

    const int tid = threadIdx.x;

    for (int i = tid; i < WIN_SIZE; i += 256) lw[i] = window[i];

    // stage tile A: coalesced float4 loads -> swizzled scalar LDS writes
    const long baseA  = (long)b * T_LEN + (long)kA * TILE_SAMP;
    const int  availA = T_LEN - kA * TILE_SAMP;          // multiple of 16
    const int  needA4 = min(SAMPLES, availA) >> 2;
    const float4* __restrict__ xgA = (const float4*)(x + baseA);
    for (int i4 = tid; i4 < needA4; i4 += 256) {
        float4 v = xgA[i4];
        int a = i4 << 2;
        lx[swz(a + 0)] = v.x;
        lx[swz(a + 1)] = v.y;
        lx[swz(a + 2)] = v.z;
        lx[swz(a + 3)] = v.w;
    }
    __syncthreads();

    // issue tile-B prefetch NOW (B tiles are always full: kB <= 45)
    float4 pf[11];
    const float4* __restrict__ xgB = (const float4*)(x + baseA + TILE_SAMP);
    if (hasB) {
        #pragma unroll
        for (int it = 0; it < 11; ++it) {
            int i4 = tid + it * 256;
            if (i4 < SAMPLES4) pf[it] = xgB[i4];
        }
    }
    __builtin_amdgcn_sched_barrier(0);   // pin: loads issue before store loop

    store_tile(lx, lw, out, b, kA, tid);

    if (!hasB) return;
    __syncthreads();                     // all waves done reading lx(A)

    #pragma unroll
    for (int it = 0; it < 11; ++it) {
        int i4 = tid + it * 256;
        if (i4 < SAMPLES4) {
            float4 v = pf[it];
            int a = i4 << 2;
            lx[swz(a + 0)] = v.x;
            lx[swz(a + 1)] = v.y;
            lx[swz(a + 2)] = v.z;
            lx[swz(a + 3)] = v.w;
        }
    }
    __syncthreads();

    store_tile(lx, lw, out, b, kA + 1, tid);
}

extern "C" void kernel_launch(void* const* d_in, const int* in_sizes, int n_in,
                              void* d_out, int out_size, void* d_ws, size_t ws_size,
                              hipStream_t stream) {
    const float* x      = (const float*)d_in[0];
    const float* window = (const float*)d_in[1];
    // d_in[2] = win_shift scalar (160) — compile-time constant here
    float* out = (float*)d_out;

    window_frame_kernel<<<NBLOCKS, 256, 0, stream>>>(x, window, out);
}